// Round 5
// baseline (630.790 us; speedup 1.0000x reference)
//
#include <hip/hip_runtime.h>
#include <hip/hip_fp16.h>
#include <stdint.h>

// SymmetricQuantLinear: out[m,n] = scale[n] * sum_k x[m,k] * (nib(k,n) - 8)
// HARNESS DTYPES (decoded from rounds 0-4 garbage magnitudes):
//   x: FLOAT32 [M][K] on device (fp16 values upconverted; fp16 not in harness
//      dtype list -> float32). Convert to fp16 in staging (cvt_pkrtz, exact).
//   packed: int32 [K/2][N], one byte per int (lo nibble = even k, hi = odd k)
//   scale: f32 [N].  Out: FLOAT32 [M][N].
// 128x128 tile, BK=32, 4 waves, mfma_f32_16x16x32_f16, scale in epilogue.

#define M_DIM 4096
#define K_DIM 4096
#define N_DIM 11008

typedef __attribute__((ext_vector_type(8))) _Float16 f16x8;
typedef __attribute__((ext_vector_type(4))) float f32x4;

__device__ __forceinline__ unsigned pack_f16_pair(float lo, float hi) {
    // v_cvt_pkrtz_f16_f32: dst.lo = lo, dst.hi = hi. Exact for fp16-origin
    // f32 values (and for small ints) -> no double rounding.
    return __builtin_bit_cast(unsigned, __builtin_amdgcn_cvt_pkrtz(lo, hi));
}

__global__ void __launch_bounds__(256) qgemm_kernel(
    const float* __restrict__ X,            // f32 [M][K]
    const int*   __restrict__ WP,           // [K/2][N]
    const float* __restrict__ WS,           // [N]
    float*       __restrict__ Out)          // f32 [M][N]
{
    __shared__ unsigned short As[128 * 40];      // [m][k] fp16, row stride 40 (pad 8)
    __shared__ unsigned short Bs[128 * 40];      // [n][k] fp16, row stride 40 (pad 8)

    const int t = threadIdx.x;
    const int w = t >> 6;        // wave 0..3
    const int l = t & 63;        // lane

    const int bn0 = blockIdx.x * 128;
    const int bm0 = blockIdx.y * 128;

    const int wr = w >> 1;       // wave row (0..1) -> 64 out rows
    const int wc = w & 1;        // wave col (0..1) -> 64 out cols

    f32x4 acc[4][4];
#pragma unroll
    for (int i = 0; i < 4; ++i)
#pragma unroll
        for (int j = 0; j < 4; ++j)
            acc[i][j] = (f32x4){0.f, 0.f, 0.f, 0.f};

    // ---- A staging: thread t covers rows {t>>2, 64+(t>>2)}, k-off (t&3)*8 ----
    const int ar = t >> 2;              // 0..63
    const int ak = (t & 3) * 8;         // 0,8,16,24
    const float* xg = X + (size_t)(bm0 + ar) * K_DIM + ak;

    // ---- B staging: thread covers cols nl, nl+1; packed rows rg*4+rr ----
    const int nl = 2 * l;               // 0..126 even
    const int rg = w;
    const int* wp0 = WP + (size_t)(rg * 4) * N_DIM + (bn0 + nl);

    const int NT = K_DIM / 32;          // 128 K-steps

    // prefetch for kt=0  (A: 8 floats per row-half = 2x float4)
    float4 a0lo = *(const float4*)(xg);
    float4 a0hi = *(const float4*)(xg + 4);
    float4 a1lo = *(const float4*)(xg + (size_t)64 * K_DIM);
    float4 a1hi = *(const float4*)(xg + (size_t)64 * K_DIM + 4);
    int2 pv[4];
#pragma unroll
    for (int rr = 0; rr < 4; ++rr)
        pv[rr] = *(const int2*)(wp0 + (size_t)rr * N_DIM);

    const int lq = l >> 4;   // k-quarter 0..3
    const int lr = l & 15;

    for (int kt = 0; kt < NT; ++kt) {
        // ---- convert + write staged A (f32 -> fp16, exact) ----
        uint4 av0 = make_uint4(pack_f16_pair(a0lo.x, a0lo.y),
                               pack_f16_pair(a0lo.z, a0lo.w),
                               pack_f16_pair(a0hi.x, a0hi.y),
                               pack_f16_pair(a0hi.z, a0hi.w));
        uint4 av1 = make_uint4(pack_f16_pair(a1lo.x, a1lo.y),
                               pack_f16_pair(a1lo.z, a1lo.w),
                               pack_f16_pair(a1hi.x, a1hi.y),
                               pack_f16_pair(a1hi.z, a1hi.w));
        *(uint4*)(&As[(size_t)ar * 40 + ak])        = av0;
        *(uint4*)(&As[(size_t)(64 + ar) * 40 + ak]) = av1;

        // ---- dequant + write staged B (fp16 exact ints) ----
        unsigned wlo[4], whi[4];
#pragma unroll
        for (int rr = 0; rr < 4; ++rr) {
            unsigned a = (unsigned)pv[rr].x;   // col nl
            unsigned b = (unsigned)pv[rr].y;   // col nl+1
            float fa0 = __uint_as_float((a & 15u) | 0x4B000000u) - 8388616.0f;
            float fa1 = __uint_as_float(((a >> 4) & 15u) | 0x4B000000u) - 8388616.0f;
            float fb0 = __uint_as_float((b & 15u) | 0x4B000000u) - 8388616.0f;
            float fb1 = __uint_as_float(((b >> 4) & 15u) | 0x4B000000u) - 8388616.0f;
            wlo[rr] = pack_f16_pair(fa0, fa1);   // k-local rg*8+2rr (even), +1 (odd)
            whi[rr] = pack_f16_pair(fb0, fb1);
        }
        *(uint4*)(&Bs[(size_t)nl * 40 + rg * 8]) =
            make_uint4(wlo[0], wlo[1], wlo[2], wlo[3]);
        *(uint4*)(&Bs[(size_t)(nl + 1) * 40 + rg * 8]) =
            make_uint4(whi[0], whi[1], whi[2], whi[3]);

        __syncthreads();   // As/Bs ready

        // ---- prefetch kt+1 (latency hides under MFMA) ----
        if (kt + 1 < NT) {
            const int k1 = (kt + 1) * 32;
            a0lo = *(const float4*)(xg + k1);
            a0hi = *(const float4*)(xg + k1 + 4);
            a1lo = *(const float4*)(xg + (size_t)64 * K_DIM + k1);
            a1hi = *(const float4*)(xg + (size_t)64 * K_DIM + k1 + 4);
#pragma unroll
            for (int rr = 0; rr < 4; ++rr)
                pv[rr] = *(const int2*)(wp0 + ((size_t)(kt + 1) * 16 + rr) * N_DIM);
        }

        // ---- fragments + MFMA (fp16) ----
        f16x8 af[4], bfr[4];
#pragma unroll
        for (int mi = 0; mi < 4; ++mi) {
            const int row = wr * 64 + mi * 16 + lr;
            af[mi] = *(const f16x8*)&As[(size_t)row * 40 + lq * 8];
        }
#pragma unroll
        for (int ni = 0; ni < 4; ++ni) {
            const int col = wc * 64 + ni * 16 + lr;
            bfr[ni] = *(const f16x8*)&Bs[(size_t)col * 40 + lq * 8];
        }
#pragma unroll
        for (int mi = 0; mi < 4; ++mi)
#pragma unroll
            for (int ni = 0; ni < 4; ++ni)
                acc[mi][ni] = __builtin_amdgcn_mfma_f32_16x16x32_f16(
                    af[mi], bfr[ni], acc[mi][ni], 0, 0, 0);

        __syncthreads();   // frag reads done; LDS free for next stage
    }

    // ---- epilogue: per-column scale, f32 store ----
#pragma unroll
    for (int ni = 0; ni < 4; ++ni) {
        const int col = bn0 + wc * 64 + ni * 16 + lr;
        const float s = WS[col];
#pragma unroll
        for (int mi = 0; mi < 4; ++mi) {
            const int row = bm0 + wr * 64 + mi * 16 + lq * 4;
#pragma unroll
            for (int i = 0; i < 4; ++i) {
                Out[(size_t)(row + i) * N_DIM + col] = acc[mi][ni][i] * s;
            }
        }
    }
}

extern "C" void kernel_launch(void* const* d_in, const int* in_sizes, int n_in,
                              void* d_out, int out_size, void* d_ws, size_t ws_size,
                              hipStream_t stream) {
    const float* X  = (const float*)d_in[0];
    const int*   WP = (const int*)d_in[1];
    const float* WS = (const float*)d_in[2];
    float*       Out = (float*)d_out;

    dim3 grid(N_DIM / 128, M_DIM / 128);   // 86 x 32
    qgemm_kernel<<<grid, 256, 0, stream>>>(X, WP, WS, Out);
}